// Round 2
// baseline (184.129 us; speedup 1.0000x reference)
//
#include <hip/hip_runtime.h>

// FDN reverb == 8-tap sparse FIR + 50/50 mix + global max-abs normalize.
// R6: SINGLE kernel launch. R5 halved the kernel work (all-b128 taps,
// no pass-B recompute) and dur_us did not move (107->111), while rocprof
// shows both kernels < 42us and ~25us combined by arithmetic -> the
// measured time is launch/timed-region overhead, not kernel body.
// So: fuse both passes into one launch with a manual grid barrier:
//   phase 1: per block, 4 adjacent chunks: LDS-staged FIR, unnormalized
//            store to out (re-read later by the SAME block -> L1/L2 hot,
//            no cross-block coherence needed), accumulate block max.
//   barrier: device-scope atomicMax(max) + release fetch_add(ctr);
//            thread 0 spins (acquire) until ctr == gridDim. Safe:
//            512 blocks, capacity >= 4 blocks/CU * 256 CU = 1024
//            co-resident (LDS 31744B -> 5/CU; VGPR <= 128 -> 4/CU).
//   phase 2: re-read own chunks, scale by 1/max, nontemporal store.
// d_ws holds {max_bits, ctr}; re-armed by an 8-byte hipMemsetAsync in
// the same captured stream (graph-capturable, stream-ordered).
#define T_LEN  8388608
#define CHUNK  4096              // outputs per staged tile
#define HALO   3840              // >= max delay (3825), multiple of 4
#define LDSF   (HALO + CHUNK)    // 7936 floats = 31744 B
#define NCHUNK (T_LEN / CHUNK)   // 2048
#define NBLOCKS 512
#define CPB    (NCHUNK / NBLOCKS) // 4 adjacent chunks per block

#define D0 1425   // %4 == 1
#define D1 1780   // %4 == 0
#define D2 1972   // %4 == 0
#define D3 2097   // %4 == 1
#define D4 2558   // %4 == 2
#define D5 2961   // %4 == 1
#define D6 3508   // %4 == 0
#define D7 3825   // %4 == 1

typedef float floatx4 __attribute__((ext_vector_type(4)));  // nontemporal store

// Read 4 consecutive floats at p - D from LDS using only aligned b128s.
// r = misalignment phase (compile-time); select w[r..r+3] is fully static.
template <int D>
__device__ __forceinline__ void tap4(const float* __restrict__ p, float v[4]) {
    constexpr int r = (4 - (D & 3)) & 3;
    const float* q = p - D - r;              // 16B-aligned (p is 0 mod 4)
    float4 w0 = *(const float4*)q;
    if constexpr (r == 0) {
        v[0] = w0.x; v[1] = w0.y; v[2] = w0.z; v[3] = w0.w;
    } else {
        float4 w1 = *(const float4*)(q + 4);
        float w[8] = {w0.x, w0.y, w0.z, w0.w, w1.x, w1.y, w1.z, w1.w};
#pragma unroll
        for (int k = 0; k < 4; ++k) v[k] = w[r + k];  // r+k compile-time
    }
}

// Compute 4 outputs at LDS pointer p (16B-aligned), coefficients c[8].
__device__ __forceinline__ float4 quad_fir(const float* __restrict__ p,
                                           const float* __restrict__ c) {
    float4 dry = *(const float4*)(p);
    float t0v[4], t1v[4], t2v[4], t3v[4], t4v[4], t5v[4], t6v[4], t7v[4];
    tap4<D0>(p, t0v);
    tap4<D1>(p, t1v);
    tap4<D2>(p, t2v);
    tap4<D3>(p, t3v);
    tap4<D4>(p, t4v);
    tap4<D5>(p, t5v);
    tap4<D6>(p, t6v);
    tap4<D7>(p, t7v);

    float4 o;
#pragma unroll
    for (int k = 0; k < 4; ++k) {
        float wet = 0.f;
        wet = fmaf(c[0], t0v[k], wet);
        wet = fmaf(c[1], t1v[k], wet);
        wet = fmaf(c[2], t2v[k], wet);
        wet = fmaf(c[3], t3v[k], wet);
        wet = fmaf(c[4], t4v[k], wet);
        wet = fmaf(c[5], t5v[k], wet);
        wet = fmaf(c[6], t6v[k], wet);
        wet = fmaf(c[7], t7v[k], wet);
        (&o.x)[k] = fmaf(0.5f, wet, 0.5f * (&dry.x)[k]);
    }
    return o;
}

// Stage [ch*CHUNK - HALO, ch*CHUNK + CHUNK) into LDS; zeros before t=0.
__device__ __forceinline__ void stage(const float* __restrict__ x, float* smem,
                                      int ch, int tid) {
    const long gs = (long)ch * CHUNK - HALO;
    for (int v4 = tid; v4 < LDSF / 4; v4 += 256) {
        long ga = gs + (long)v4 * 4;
        float4 val = make_float4(0.f, 0.f, 0.f, 0.f);
        if (ga >= 0) val = *(const float4*)(x + ga);
        *(float4*)(smem + v4 * 4) = val;
    }
}

__device__ __forceinline__ void load_coeffs(const float* __restrict__ g,
                                            const float* __restrict__ Q,
                                            float* csh, int tid) {
    if (tid < 8) {
        float s = 0.f;
#pragma unroll
        for (int j = 0; j < 8; ++j) s += Q[j * 8 + tid];
        csh[tid] = s * g[tid];
    }
}

__global__ __launch_bounds__(256) void fdn_fused(
    const float* __restrict__ x, const float* __restrict__ g,
    const float* __restrict__ Q, unsigned int* __restrict__ gsync,
    float* __restrict__ out) {
    __shared__ __align__(16) float smem[LDSF];
    __shared__ float csh[8];
    __shared__ float wmax[4];
    __shared__ float sinv;

    const int tid = threadIdx.x;
    const int p   = blockIdx.x;
    // XCD k (p%8) owns contiguous chunks [k*256,(k+1)*256); each block takes
    // 4 ADJACENT chunks so successive stages' halos are L2-hot.
    const int c0 = (p & 7) * (NCHUNK / 8) + (p >> 3) * CPB;

    load_coeffs(g, Q, csh, tid);

    float c[8];
    float m = 0.f;
#pragma unroll
    for (int cc = 0; cc < CPB; ++cc) {
        stage(x, smem, c0 + cc, tid);
        __syncthreads();                 // covers csh on first iteration
        if (cc == 0) {
#pragma unroll
            for (int n = 0; n < 8; ++n) c[n] = csh[n];
        }
        const int base = (c0 + cc) * CHUNK;
#pragma unroll
        for (int i = 0; i < CHUNK / 1024; ++i) {
            const int j = i * 1024 + tid * 4;
            float4 o = quad_fir(smem + HALO + j, c);
            m = fmaxf(m, fmaxf(fmaxf(fabsf(o.x), fabsf(o.y)),
                               fmaxf(fabsf(o.z), fabsf(o.w))));
            *(float4*)(out + base + j) = o;   // unnormalized; re-read by us
        }
        __syncthreads();                 // before restaging smem
    }

    // block max
#pragma unroll
    for (int off = 32; off > 0; off >>= 1) m = fmaxf(m, __shfl_down(m, off, 64));
    if ((tid & 63) == 0) wmax[tid >> 6] = m;
    __syncthreads();

    // grid barrier: publish max (device scope), arrive, spin, broadcast 1/max
    if (tid == 0) {
        float bm = fmaxf(fmaxf(wmax[0], wmax[1]), fmaxf(wmax[2], wmax[3]));
        atomicMax(gsync, __float_as_uint(bm));   // fabs>=0: uint order == float
        __threadfence();                          // max visible before arrive
        __hip_atomic_fetch_add(gsync + 1, 1u, __ATOMIC_RELEASE,
                               __HIP_MEMORY_SCOPE_AGENT);
        while (__hip_atomic_load(gsync + 1, __ATOMIC_ACQUIRE,
                                 __HIP_MEMORY_SCOPE_AGENT) < (unsigned)NBLOCKS)
            __builtin_amdgcn_s_sleep(8);
        sinv = 1.0f / __uint_as_float(__hip_atomic_load(
                         gsync, __ATOMIC_RELAXED, __HIP_MEMORY_SCOPE_AGENT));
    }
    __syncthreads();
    const float inv = sinv;

    // phase 2: scale own chunks (reads hit own CU's L1/L2), final NT store
#pragma unroll
    for (int cc = 0; cc < CPB; ++cc) {
        const int base = (c0 + cc) * CHUNK;
#pragma unroll
        for (int i = 0; i < CHUNK / 1024; ++i) {
            const int j = i * 1024 + tid * 4;
            float4 v = *(const float4*)(out + base + j);
            floatx4 ov;
            ov.x = v.x * inv; ov.y = v.y * inv;
            ov.z = v.z * inv; ov.w = v.w * inv;
            __builtin_nontemporal_store(ov, (floatx4*)(out + base + j));
        }
    }
}

extern "C" void kernel_launch(void* const* d_in, const int* in_sizes, int n_in,
                              void* d_out, int out_size, void* d_ws, size_t ws_size,
                              hipStream_t stream) {
    const float* x = (const float*)d_in[0];       // input_sig [1, T]
    const float* g = (const float*)d_in[1];       // feedback_gain [8]
    const float* Q = (const float*)d_in[2];       // orthogonal_matrix [8,8]
    float* out = (float*)d_out;
    unsigned int* gsync = (unsigned int*)d_ws;    // {max_bits, arrive_ctr}

    // re-arm the barrier each replay (stream-ordered, graph-capturable)
    hipMemsetAsync(d_ws, 0, 2 * sizeof(unsigned int), stream);
    fdn_fused<<<dim3(NBLOCKS), dim3(256), 0, stream>>>(x, g, Q, gsync, out);
}

// Round 3
// 109.039 us; speedup vs baseline: 1.6886x; 1.6886x over previous
//
#include <hip/hip_runtime.h>

// FDN reverb == 8-tap sparse FIR + 50/50 mix + global max-abs normalize.
// R7: revert R6's fusion (512-block grid-barrier kernel was latency-bound:
// 2 blocks/CU, 13% HBM, 95-112us). Measured model across R1/R5/R6:
//   dur_us ~= our kernel time + ~86us of harness poison fills (2x 268MB
//   fillBufferAligned @ ~43us, visible in every round's top-5).
// So minimize kernel time. Minimal-HBM structure is R1's:
//   pass A: LDS-staged FIR, block max only -> slots[blk]. 33.5MB HBM read,
//           no output store.
//   pass B: reduce slots -> 1/max, recompute FIR (x re-read is L3-hot:
//           33.5MB << 256MB Infinity Cache, just touched by pass A),
//           single 33.5MB nontemporal write.
// Net HBM ~= 67MB vs R5's ~110MB (R1 measured 4us faster than R5).
// Taps use the R5 lever: every LDS tap read is an aligned ds_read_b128
// pair with compile-time register select (old scalar/b64 odd-tap reads
// at 16B lane stride were 8-way bank conflicts).
#define T_LEN 8388608
#define CHUNK 4096               // outputs per block
#define HALO  3840               // >= max delay (3825), multiple of 4
#define LDSF  (HALO + CHUNK)     // 7936 floats = 31744 B -> 5 blocks/CU
#define NBLK  (T_LEN / CHUNK)    // 2048 blocks

#define D0 1425   // %4 == 1
#define D1 1780   // %4 == 0
#define D2 1972   // %4 == 0
#define D3 2097   // %4 == 1
#define D4 2558   // %4 == 2
#define D5 2961   // %4 == 1
#define D6 3508   // %4 == 0
#define D7 3825   // %4 == 1

typedef float floatx4 __attribute__((ext_vector_type(4)));  // nontemporal store

__device__ __forceinline__ int swz(int b) {
    // phys block -> logical chunk: XCD k (b%8) owns contiguous [k*256,(k+1)*256)
    return (b & 7) * (NBLK / 8) + (b >> 3);
}

// Read 4 consecutive floats at p - D from LDS using only aligned b128s.
// r = misalignment phase (compile-time); select w[r..r+3] is fully static.
template <int D>
__device__ __forceinline__ void tap4(const float* __restrict__ p, float v[4]) {
    constexpr int r = (4 - (D & 3)) & 3;
    const float* q = p - D - r;              // 16B-aligned (p is 0 mod 4)
    float4 w0 = *(const float4*)q;
    if constexpr (r == 0) {
        v[0] = w0.x; v[1] = w0.y; v[2] = w0.z; v[3] = w0.w;
    } else {
        float4 w1 = *(const float4*)(q + 4);
        float w[8] = {w0.x, w0.y, w0.z, w0.w, w1.x, w1.y, w1.z, w1.w};
#pragma unroll
        for (int k = 0; k < 4; ++k) v[k] = w[r + k];  // r+k compile-time
    }
}

// Compute 4 outputs at LDS pointer p (16B-aligned), coefficients c[8].
__device__ __forceinline__ float4 quad_fir(const float* __restrict__ p,
                                           const float* __restrict__ c) {
    float4 dry = *(const float4*)(p);
    float t0v[4], t1v[4], t2v[4], t3v[4], t4v[4], t5v[4], t6v[4], t7v[4];
    tap4<D0>(p, t0v);
    tap4<D1>(p, t1v);
    tap4<D2>(p, t2v);
    tap4<D3>(p, t3v);
    tap4<D4>(p, t4v);
    tap4<D5>(p, t5v);
    tap4<D6>(p, t6v);
    tap4<D7>(p, t7v);

    float4 o;
#pragma unroll
    for (int k = 0; k < 4; ++k) {
        float wet = 0.f;
        wet = fmaf(c[0], t0v[k], wet);
        wet = fmaf(c[1], t1v[k], wet);
        wet = fmaf(c[2], t2v[k], wet);
        wet = fmaf(c[3], t3v[k], wet);
        wet = fmaf(c[4], t4v[k], wet);
        wet = fmaf(c[5], t5v[k], wet);
        wet = fmaf(c[6], t6v[k], wet);
        wet = fmaf(c[7], t7v[k], wet);
        (&o.x)[k] = fmaf(0.5f, wet, 0.5f * (&dry.x)[k]);
    }
    return o;
}

// Stage [blk*CHUNK - HALO, blk*CHUNK + CHUNK) into LDS; zeros before t=0.
__device__ __forceinline__ void stage(const float* __restrict__ x, float* smem,
                                      int blk, int tid) {
    const long gs = (long)blk * CHUNK - HALO;
    for (int v4 = tid; v4 < LDSF / 4; v4 += 256) {
        long ga = gs + (long)v4 * 4;
        float4 val = make_float4(0.f, 0.f, 0.f, 0.f);
        if (ga >= 0) val = *(const float4*)(x + ga);
        *(float4*)(smem + v4 * 4) = val;
    }
}

__device__ __forceinline__ void load_coeffs(const float* __restrict__ g,
                                            const float* __restrict__ Q,
                                            float* csh, int tid) {
    if (tid < 8) {
        float s = 0.f;
#pragma unroll
        for (int j = 0; j < 8; ++j) s += Q[j * 8 + tid];
        csh[tid] = s * g[tid];
    }
}

// Pass A: FIR + block max -> slots[blk]. No output store.
__global__ __launch_bounds__(256) void fdn_max(
    const float* __restrict__ x, const float* __restrict__ g,
    const float* __restrict__ Q, float* __restrict__ slots) {
    __shared__ __align__(16) float smem[LDSF];
    __shared__ float csh[8];
    __shared__ float wmax[4];

    const int tid = threadIdx.x;
    const int blk = swz(blockIdx.x);

    load_coeffs(g, Q, csh, tid);
    stage(x, smem, blk, tid);
    __syncthreads();

    float c[8];
#pragma unroll
    for (int n = 0; n < 8; ++n) c[n] = csh[n];

    float m = 0.f;
#pragma unroll
    for (int i = 0; i < CHUNK / 1024; ++i) {
        const float* p = smem + HALO + i * 1024 + tid * 4;
        float4 o = quad_fir(p, c);
        m = fmaxf(m, fmaxf(fmaxf(fabsf(o.x), fabsf(o.y)),
                           fmaxf(fabsf(o.z), fabsf(o.w))));
    }

#pragma unroll
    for (int off = 32; off > 0; off >>= 1) m = fmaxf(m, __shfl_down(m, off, 64));
    if ((tid & 63) == 0) wmax[tid >> 6] = m;
    __syncthreads();
    if (tid == 0)
        slots[blk] = fmaxf(fmaxf(wmax[0], wmax[1]), fmaxf(wmax[2], wmax[3]));
}

// Pass B: reduce slots -> inv, recompute FIR (x is L3-hot), scale, NT write.
__global__ __launch_bounds__(256) void fdn_write(
    const float* __restrict__ x, const float* __restrict__ g,
    const float* __restrict__ Q, const float* __restrict__ slots,
    float* __restrict__ out) {
    __shared__ __align__(16) float smem[LDSF];
    __shared__ float csh[8];
    __shared__ float wmax[4];

    const int tid = threadIdx.x;
    const int blk = swz(blockIdx.x);

    load_coeffs(g, Q, csh, tid);

    // each thread covers 8 of the 2048 slots (two float4 loads)
    float4 s0 = *(const float4*)(slots + tid * 8);
    float4 s1 = *(const float4*)(slots + tid * 8 + 4);

    stage(x, smem, blk, tid);

    float m = fmaxf(fmaxf(fmaxf(s0.x, s0.y), fmaxf(s0.z, s0.w)),
                    fmaxf(fmaxf(s1.x, s1.y), fmaxf(s1.z, s1.w)));
#pragma unroll
    for (int off = 32; off > 0; off >>= 1) m = fmaxf(m, __shfl_down(m, off, 64));
    if ((tid & 63) == 0) wmax[tid >> 6] = m;
    __syncthreads();   // covers staging + wmax

    const float inv = 1.0f / fmaxf(fmaxf(wmax[0], wmax[1]),
                                   fmaxf(wmax[2], wmax[3]));
    float c[8];
#pragma unroll
    for (int n = 0; n < 8; ++n) c[n] = csh[n];

    const int base = blk * CHUNK;
#pragma unroll
    for (int i = 0; i < CHUNK / 1024; ++i) {
        const int j = i * 1024 + tid * 4;
        const float* p = smem + HALO + j;
        float4 o = quad_fir(p, c);
        floatx4 ov;
        ov.x = o.x * inv; ov.y = o.y * inv;
        ov.z = o.z * inv; ov.w = o.w * inv;
        __builtin_nontemporal_store(ov, (floatx4*)(out + base + j));
    }
}

extern "C" void kernel_launch(void* const* d_in, const int* in_sizes, int n_in,
                              void* d_out, int out_size, void* d_ws, size_t ws_size,
                              hipStream_t stream) {
    const float* x = (const float*)d_in[0];       // input_sig [1, T]
    const float* g = (const float*)d_in[1];       // feedback_gain [8]
    const float* Q = (const float*)d_in[2];       // orthogonal_matrix [8,8]
    float* out = (float*)d_out;
    float* slots = (float*)d_ws;                  // 2048 per-block maxes
                                                  // (written unconditionally by
                                                  //  pass A before pass B reads)

    fdn_max  <<<dim3(NBLK), dim3(256), 0, stream>>>(x, g, Q, slots);
    fdn_write<<<dim3(NBLK), dim3(256), 0, stream>>>(x, g, Q, slots, out);
}